// Round 9
// baseline (5032.805 us; speedup 1.0000x reference)
//
#include <hip/hip_runtime.h>
#include <hip/hip_bf16.h>

#define B_  64
#define T_  1024
#define D_  512
#define H_  1024
#define G4H (4 * H_)
#define NWG 256
#define SENTQ 0x7FC07FC07FC07FC0ull   // bf16 NaN x4: unreachable, |h|<1

typedef __attribute__((ext_vector_type(8))) short bf16x8;
typedef __attribute__((ext_vector_type(4))) float f32x4;
typedef __attribute__((ext_vector_type(4))) int   i32x4;

__device__ __forceinline__ short f2bf(float f) {
    union { float f; unsigned int u; } v; v.f = f;
    unsigned int r = v.u + 0x7FFFu + ((v.u >> 16) & 1u);  // RNE
    return (short)(r >> 16);
}
__device__ __forceinline__ float sigmoid_f(float x) { return 1.0f / (1.0f + __expf(-x)); }
__device__ __forceinline__ float tanh_f(float x) {
    float ax = fabsf(x);
    float e  = __expf(-2.0f * ax);
    return copysignf((1.0f - e) / (1.0f + e), x);
}
__device__ __forceinline__ unsigned long long aloadq(const unsigned long long* p) {
    return __hip_atomic_load(p, __ATOMIC_RELAXED, __HIP_MEMORY_SCOPE_AGENT);
}
__device__ __forceinline__ void astoreq(unsigned long long* p, unsigned long long v) {
    __hip_atomic_store(p, v, __ATOMIC_RELAXED, __HIP_MEMORY_SCOPE_AGENT);
}

// 8 x 16B loads, L1-bypassed (sc0) -> served by the XCD-local L2. Single asm
// block with internal vmcnt(0): outputs are valid when the block retires
// (data-dep ordering; avoids the rule-18 hoist trap).
__device__ __forceinline__ void load8_sc0(const void* base, i32x4 q[8]) {
    asm volatile(
        "global_load_dwordx4 %0, %8, off sc0\n\t"
        "global_load_dwordx4 %1, %8, off offset:64 sc0\n\t"
        "global_load_dwordx4 %2, %8, off offset:128 sc0\n\t"
        "global_load_dwordx4 %3, %8, off offset:192 sc0\n\t"
        "global_load_dwordx4 %4, %8, off offset:256 sc0\n\t"
        "global_load_dwordx4 %5, %8, off offset:320 sc0\n\t"
        "global_load_dwordx4 %6, %8, off offset:384 sc0\n\t"
        "global_load_dwordx4 %7, %8, off offset:448 sc0\n\t"
        "s_waitcnt vmcnt(0)"
        : "=&v"(q[0]), "=&v"(q[1]), "=&v"(q[2]), "=&v"(q[3]),
          "=&v"(q[4]), "=&v"(q[5]), "=&v"(q[6]), "=&v"(q[7])
        : "v"(base) : "memory");
}
// 16B store, sc0: write-through/bypass L1, lands in the XCD L2 -> visible to
// sc0 readers on the same XCD. (R8 used plain stores here - hang suspect #1.)
__device__ __forceinline__ void store16_sc0(void* p, i32x4 v) {
    asm volatile("global_store_dwordx4 %0, %1, off sc0" :: "v"(p), "v"(v) : "memory");
}

// R9 = R8 (recurrence closed inside one XCD) with the hang vectors closed:
// full-coverage init/re-sentinel (R8 covered only HALF the qwords), sc0 on
// producer stores, and EVERY spin loop bounded (handshake cap -> agent
// fallback; data-poll cap -> terminate wrong instead of hanging).
__global__ void __launch_bounds__(256, 1)
lstm_persistent(const float* __restrict__ x,     // [B,T,D]
                const float* __restrict__ Wx,    // [D,4H]
                const float* __restrict__ Wh,    // [H,4H]
                const float* __restrict__ bias,  // [4H] (i,f,g,o)
                float* __restrict__ y,           // [B,T,H]
                short* __restrict__ h_buf,       // ws: [4][B][H] bf16 ring
                int* __restrict__ tab)           // ws: [NWG*16] xcc table
{
    const int wg   = blockIdx.x;
    const int tid  = threadIdx.x;
    const int lane = tid & 63;
    const int wv   = tid >> 6;
    const int g    = wg & 7;            // group; == XCD if round-robin dispatch
    const int jt   = wg >> 3;           // hidden tile 0..31 (32 cols each)
    const int j0   = jt * 32;
    const int bg   = g * 8;             // group's 8 batches

    const int c    = lane & 15;
    const int kblk = lane >> 4;
    const int b_a  = bg + (c & 7);      // A rows 8-15 duplicate 0-7 (ignored)
    const int kh0  = wv * 256;          // wave's K-slice of H
    const int kx0  = wv * 128;          // wave's K-slice of D

    __shared__ bf16x8 hw[4][4][8][64];  // 128 KB: h-weight col-tiles 0..3
    __shared__ float  gbuf[4][8][132];  // partial gates
    __shared__ int    s_local;

    // col of col-tile ct (0..7): gate = ct>>1, within-gate = (ct&1)*16 + c
#pragma unroll
    for (int ct = 0; ct < 4; ++ct) {
        const int col = (ct >> 1) * H_ + j0 + (ct & 1) * 16 + c;
#pragma unroll
        for (int ks = 0; ks < 8; ++ks) {
            bf16x8 tf;
#pragma unroll
            for (int e = 0; e < 8; ++e)
                tf[e] = f2bf(Wh[(size_t)(kh0 + ks * 32 + kblk * 8 + e) * G4H + col]);
            hw[wv][ct][ks][lane] = tf;
        }
    }
    bf16x8 whr[4][8];                   // h-weight col-tiles 4..7 -> regs
#pragma unroll
    for (int ct = 4; ct < 8; ++ct) {
        const int col = (ct >> 1) * H_ + j0 + (ct & 1) * 16 + c;
#pragma unroll
        for (int ks = 0; ks < 8; ++ks) {
            bf16x8 tf;
#pragma unroll
            for (int e = 0; e < 8; ++e)
                tf[e] = f2bf(Wh[(size_t)(kh0 + ks * 32 + kblk * 8 + e) * G4H + col]);
            whr[ct - 4][ks] = tf;
        }
    }
    bf16x8 wxf[8][4];                   // x-weights -> regs
#pragma unroll
    for (int ct = 0; ct < 8; ++ct) {
        const int col = (ct >> 1) * H_ + j0 + (ct & 1) * 16 + c;
#pragma unroll
        for (int ks = 0; ks < 4; ++ks) {
            bf16x8 tf;
#pragma unroll
            for (int e = 0; e < 8; ++e)
                tf[e] = f2bf(Wx[(size_t)(kx0 + ks * 32 + kblk * 8 + e) * G4H + col]);
            wxf[ct][ks] = tf;
        }
    }
#pragma unroll
    for (int a = 0; a < 4; ++a)
#pragma unroll
        for (int ks = 0; ks < 8; ++ks)
            asm volatile("" : "+v"(whr[a][ks]));   // pin vs rematerialization
#pragma unroll
    for (int a = 0; a < 8; ++a)
#pragma unroll
        for (int ks = 0; ks < 4; ++ks)
            asm volatile("" : "+v"(wxf[a][ks]));

    // ---- ring init, FULL coverage: 4 slots x 8 rows x 8 qwords = 256 = tid.
    // Agent stores: coherent for both paths (local L2 updated-or-invalidated;
    // sc0 miss refills from IC which holds the init value).
    {
        int slot = tid >> 6, row = (tid >> 3) & 7, q = tid & 7;
        unsigned long long* p = (unsigned long long*)
            (h_buf + slot * (B_ * H_) + (size_t)(bg + row) * H_ + j0 + q * 4);
        astoreq(p, slot == 0 ? 0ull : SENTQ);
    }

    int xcc;
    asm volatile("s_getreg_b32 %0, hwreg(HW_REG_XCC_ID)" : "=s"(xcc));
    __syncthreads();                    // drains vmcnt: init stores acked
    if (tid == 0) {
        __hip_atomic_store(&tab[wg * 16], xcc + 1,
                           __ATOMIC_RELAXED, __HIP_MEMORY_SCOPE_AGENT);
        int ok = 1;
        for (int m = 0; m < 32; ++m) {
            const int* e = &tab[(g + m * 8) * 16];
            int v = 0;
            for (long cap = 1L << 26; cap > 0; --cap) {   // bounded: cap -> v=0
                v = __hip_atomic_load(e, __ATOMIC_RELAXED, __HIP_MEMORY_SCOPE_AGENT);
                if (v != 0) break;
            }
            ok &= (v == xcc + 1);       // cap => v==0 => ok=0 => agent fallback
        }
        s_local = ok;
    }
    __syncthreads();
    const bool isloc = (s_local != 0);  // group-uniform (final tab values only)

    // epilogue mapping: all 256 threads -> (batch eb 0..7, hidden ej 0..31)
    const int eb = tid >> 5;
    const int ej = tid & 31;
    const float bi  = bias[0 * H_ + j0 + ej];
    const float bfv = bias[1 * H_ + j0 + ej];
    const float bgv = bias[2 * H_ + j0 + ej];
    const float bo  = bias[3 * H_ + j0 + ej];
    const int b_glob = bg + eb;
    const int j_glob = j0 + ej;

    float cstate = 0.0f;

    // x-part for t=0 (prologue; one-time HBM stall is fine)
    f32x4 acc[8];
#pragma unroll
    for (int a = 0; a < 8; ++a) acc[a] = (f32x4){0.f, 0.f, 0.f, 0.f};
    {
        const float* xr = x + ((size_t)b_a * T_ + 0) * D_ + kx0 + kblk * 8;
#pragma unroll
        for (int ks = 0; ks < 4; ++ks) {
            f32x4 lo = *(const f32x4*)(xr + ks * 32);
            f32x4 hi = *(const f32x4*)(xr + ks * 32 + 4);
            bf16x8 xa;
#pragma unroll
            for (int e = 0; e < 4; ++e) { xa[e] = f2bf(lo[e]); xa[e + 4] = f2bf(hi[e]); }
#pragma unroll
            for (int ct = 0; ct < 8; ++ct)
                acc[ct] = __builtin_amdgcn_mfma_f32_16x16x32_bf16(xa, wxf[ct][ks], acc[ct], 0, 0, 0);
        }
    }

#pragma unroll 1
    for (int t = 0; t < T_; ++t) {
        // (A) issue x loads for t+1 NOW: HBM latency hides under poll+compute
        f32x4 xl[4], xh[4];
        if (t + 1 < T_) {
            const float* xr = x + ((size_t)b_a * T_ + (t + 1)) * D_ + kx0 + kblk * 8;
#pragma unroll
            for (int ks = 0; ks < 4; ++ks) {
                xl[ks] = *(const f32x4*)(xr + ks * 32);
                xh[ks] = *(const f32x4*)(xr + ks * 32 + 4);
            }
        }

        // (B) poll h_t (data IS the flag); lanes c>=8 don't gate; BOUNDED
        const short* hq = h_buf + (t & 3) * (B_ * H_)
                        + (size_t)b_a * H_ + kh0 + kblk * 8;
        i32x4 qv[8];
        if (isloc) {
            for (int cap = 1 << 18; cap > 0; --cap) {
                load8_sc0(hq, qv);
                bool mine = true;
#pragma unroll
                for (int k2 = 0; k2 < 8; ++k2) {
                    union { i32x4 i; unsigned long long q[2]; } u; u.i = qv[k2];
                    mine &= (u.q[0] != SENTQ) & (u.q[1] != SENTQ);
                }
                if (__all((int)(mine | (c >= 8)))) break;
                __builtin_amdgcn_s_sleep(1);
            }
        } else {
            const unsigned long long* hqq = (const unsigned long long*)hq;
            for (int cap = 1 << 18; cap > 0; --cap) {
                union { i32x4 i; unsigned long long q[2]; } u[8];
#pragma unroll
                for (int k2 = 0; k2 < 8; ++k2) {
                    u[k2].q[0] = aloadq(hqq + k2 * 8);
                    u[k2].q[1] = aloadq(hqq + k2 * 8 + 1);
                }
                bool mine = true;
#pragma unroll
                for (int k2 = 0; k2 < 8; ++k2)
                    mine &= (u[k2].q[0] != SENTQ) & (u[k2].q[1] != SENTQ);
                if (__all((int)(mine | (c >= 8)))) {
#pragma unroll
                    for (int k2 = 0; k2 < 8; ++k2) qv[k2] = u[k2].i;
                    break;
                }
                __builtin_amdgcn_s_sleep(1);
            }
        }

        // (C) h MFMAs: 8 ks x 8 col-tiles (4 LDS + 4 reg), 8 acc chains
#pragma unroll
        for (int ks = 0; ks < 8; ++ks) {
            union { i32x4 i; bf16x8 v; } ua; ua.i = qv[ks];
            acc[0] = __builtin_amdgcn_mfma_f32_16x16x32_bf16(ua.v, hw[wv][0][ks][lane], acc[0], 0, 0, 0);
            acc[1] = __builtin_amdgcn_mfma_f32_16x16x32_bf16(ua.v, hw[wv][1][ks][lane], acc[1], 0, 0, 0);
            acc[2] = __builtin_amdgcn_mfma_f32_16x16x32_bf16(ua.v, hw[wv][2][ks][lane], acc[2], 0, 0, 0);
            acc[3] = __builtin_amdgcn_mfma_f32_16x16x32_bf16(ua.v, hw[wv][3][ks][lane], acc[3], 0, 0, 0);
            acc[4] = __builtin_amdgcn_mfma_f32_16x16x32_bf16(ua.v, whr[0][ks], acc[4], 0, 0, 0);
            acc[5] = __builtin_amdgcn_mfma_f32_16x16x32_bf16(ua.v, whr[1][ks], acc[5], 0, 0, 0);
            acc[6] = __builtin_amdgcn_mfma_f32_16x16x32_bf16(ua.v, whr[2][ks], acc[6], 0, 0, 0);
            acc[7] = __builtin_amdgcn_mfma_f32_16x16x32_bf16(ua.v, whr[3][ks], acc[7], 0, 0, 0);
        }

        // (D) partials -> LDS (D layout: col=lane&15, row=kblk*4+r; rows<8)
        if (kblk < 2) {
#pragma unroll
            for (int ct = 0; ct < 8; ++ct)
#pragma unroll
                for (int r = 0; r < 4; ++r)
                    gbuf[wv][kblk * 4 + r][ct * 16 + c] = acc[ct][r];
        }
        // drain: orders last iter's re-sentinel/y/x traffic before this
        // iter's h-data store (sentinel-before-data invariant)
        asm volatile("s_waitcnt vmcnt(0)" ::: "memory");
        __syncthreads();

        // (E) reduce 4 wave-partials + activations
        float gi = ((gbuf[0][eb][ 0 + ej] + gbuf[1][eb][ 0 + ej])
                  + (gbuf[2][eb][ 0 + ej] + gbuf[3][eb][ 0 + ej])) + bi;
        float gf = ((gbuf[0][eb][32 + ej] + gbuf[1][eb][32 + ej])
                  + (gbuf[2][eb][32 + ej] + gbuf[3][eb][32 + ej])) + bfv;
        float gg = ((gbuf[0][eb][64 + ej] + gbuf[1][eb][64 + ej])
                  + (gbuf[2][eb][64 + ej] + gbuf[3][eb][64 + ej])) + bgv;
        float go = ((gbuf[0][eb][96 + ej] + gbuf[1][eb][96 + ej])
                  + (gbuf[2][eb][96 + ej] + gbuf[3][eb][96 + ej])) + bo;

        float I = sigmoid_f(gi);
        float F = sigmoid_f(gf);
        float G = tanh_f(gg);
        float O = sigmoid_f(go);
        cstate = F * cstate + I * G;
        float hval = O * tanh_f(cstate);

        // (F) h store = the signal, issued BEFORE sync2 (earliest visibility)
        unsigned int mybf = (unsigned int)(unsigned short)f2bf(hval);
        unsigned int p01  = mybf | (((unsigned int)__shfl_xor((int)mybf, 1, 64)) << 16);
        unsigned int p23  = (unsigned int)__shfl_xor((int)p01, 2, 64);
        unsigned int p45  = (unsigned int)__shfl_xor((int)p01, 4, 64);
        unsigned int p67  = (unsigned int)__shfl_xor((int)p01, 6, 64);
        if (t + 1 < T_) {
            short* hp = h_buf + ((t + 1) & 3) * (B_ * H_)
                      + (size_t)b_glob * H_ + j_glob;
            if (isloc) {
                if ((ej & 7) == 0) {
                    i32x4 v = { (int)p01, (int)p23, (int)p45, (int)p67 };
                    store16_sc0(hp, v);
                }
            } else {
                if ((ej & 3) == 0)
                    astoreq((unsigned long long*)hp,
                            (unsigned long long)p01 | ((unsigned long long)p23 << 32));
            }
        }
        __syncthreads();   // sync2: gbuf reads done before next iter's writes

        // (G) tail (off critical path): y, re-sentinel slot t+3, consume x
        y[((size_t)b_glob * T_ + t) * H_ + j_glob] = hval;

        if (t + 1 < T_) {
            if (isloc) {
                if (tid < 32) {       // 8 rows x 4 x 16B = FULL 64B/row
                    int row = tid >> 2, q16 = tid & 3;
                    short* sp = h_buf + ((t + 3) & 3) * (B_ * H_)
                              + (size_t)(bg + row) * H_ + j0 + q16 * 8;
                    i32x4 s4 = { (int)0x7FC07FC0, (int)0x7FC07FC0,
                                 (int)0x7FC07FC0, (int)0x7FC07FC0 };
                    store16_sc0(sp, s4);
                }
            } else {
                if (tid < 64) {       // 8 rows x 8 x 8B = FULL
                    int row = tid >> 3, q = tid & 7;
                    short* sp = h_buf + ((t + 3) & 3) * (B_ * H_)
                              + (size_t)(bg + row) * H_ + j0 + q * 4;
                    astoreq((unsigned long long*)sp, SENTQ);
                }
            }
        }

#pragma unroll
        for (int a = 0; a < 8; ++a) acc[a] = (f32x4){0.f, 0.f, 0.f, 0.f};
        if (t + 1 < T_) {
#pragma unroll
            for (int ks = 0; ks < 4; ++ks) {
                bf16x8 xa;
#pragma unroll
                for (int e = 0; e < 4; ++e) { xa[e] = f2bf(xl[ks][e]); xa[e + 4] = f2bf(xh[ks][e]); }
#pragma unroll
                for (int ct = 0; ct < 8; ++ct)
                    acc[ct] = __builtin_amdgcn_mfma_f32_16x16x32_bf16(xa, wxf[ct][ks], acc[ct], 0, 0, 0);
            }
        }
    }
}

extern "C" void kernel_launch(void* const* d_in, const int* in_sizes, int n_in,
                              void* d_out, int out_size, void* d_ws, size_t ws_size,
                              hipStream_t stream)
{
    const float* x    = (const float*)d_in[0];
    const float* Wx   = (const float*)d_in[1];
    const float* Wh   = (const float*)d_in[2];
    const float* bias = (const float*)d_in[3];
    float* y = (float*)d_out;

    const size_t ring_bytes = (size_t)4 * B_ * H_ * sizeof(short);  // 512 KB
    short* h_buf = (short*)d_ws;
    int*   tab   = (int*)((char*)d_ws + ring_bytes);

    // tab MUST be zeroed every call (stale xcc entries would corrupt the
    // handshake on replays). Ring is fully re-inited in-kernel.
    hipMemsetAsync(tab, 0, NWG * 16 * sizeof(int), stream);

    lstm_persistent<<<dim3(NWG), dim3(256), 0, stream>>>(
        x, Wx, Wh, bias, y, h_buf, tab);
}

// Round 10
// 3282.119 us; speedup vs baseline: 1.5334x; 1.5334x over previous
//
#include <hip/hip_runtime.h>
#include <hip/hip_bf16.h>

#define B_  64
#define T_  1024
#define D_  512
#define H_  1024
#define G4H (4 * H_)
#define NWG 256
#define SENTQ 0x7FC07FC07FC07FC0ull   // bf16 NaN x4: unreachable, |h|<1

typedef __attribute__((ext_vector_type(8))) short bf16x8;
typedef __attribute__((ext_vector_type(4))) float f32x4;

__device__ __forceinline__ short f2bf(float f) {
    union { float f; unsigned int u; } v; v.f = f;
    unsigned int r = v.u + 0x7FFFu + ((v.u >> 16) & 1u);  // RNE
    return (short)(r >> 16);
}
__device__ __forceinline__ float sigmoid_f(float x) { return 1.0f / (1.0f + __expf(-x)); }
__device__ __forceinline__ float tanh_f(float x) {
    float ax = fabsf(x);
    float e  = __expf(-2.0f * ax);
    return copysignf((1.0f - e) / (1.0f + e), x);
}
__device__ __forceinline__ unsigned long long aloadq(const unsigned long long* p) {
    return __hip_atomic_load(p, __ATOMIC_RELAXED, __HIP_MEMORY_SCOPE_AGENT);
}
__device__ __forceinline__ void astoreq(unsigned long long* p, unsigned long long v) {
    __hip_atomic_store(p, v, __ATOMIC_RELAXED, __HIP_MEMORY_SCOPE_AGENT);
}

// init: slot0 = 0.0 (this IS h_0; zeros are layout-independent), slots1..3 =
// sentinel. 512 KB total = 4 slots x 128 KB.
__global__ void init_hbuf(unsigned int* p) {
    int i = blockIdx.x * 256 + threadIdx.x;       // 131072 u32
    p[i] = (i < (B_ * H_ / 2)) ? 0u : 0x7FC07FC0u;
}

// R10 = R7 (dataflow sentinel ring, IC agent path, 16-batch groups) with the
// h exchange layout TRANSPOSED for coalescing:
//   h[slot][group bt][chunk q=j>>3][batch b][8 shorts], qword granule.
// R7/R9's [B][H] layout made every h load/poll instruction a 64-line scatter
// (16 rows x 2KB stride); 1024 waves re-issuing those continuously congested
// L2/IC by request COUNT - the invariant ~4.5us/step across R5-R9 protocols
// (R9 proved locality doesn't matter: WRITE halved, perf didn't). Now one
// load instruction covers a contiguous 1KB block (~16 lines, 4x fewer; poll
// traffic ~8x lower). MFMA fragments, sentinel protocol, ordering proofs and
// arithmetic are byte-identical to R7.
__global__ void __launch_bounds__(256, 1)
lstm_persistent(const float* __restrict__ x,     // [B,T,D]
                const float* __restrict__ Wx,    // [D,4H]
                const float* __restrict__ Wh,    // [H,4H]
                const float* __restrict__ bias,  // [4H] (i,f,g,o)
                float* __restrict__ y,           // [B,T,H]
                short* __restrict__ h_buf)       // ws: [4][4][128][16][8] bf16
{
    const int wg   = blockIdx.x;
    const int tid  = threadIdx.x;
    const int lane = tid & 63;
    const int wv   = tid >> 6;
    const int bt   = (wg >> 1) & 3;               // batch group 0..3
    const int jt   = ((wg & 1) << 5) | (wg >> 3); // hidden tile 0..63
    const int j0   = jt * 16;

    const int c    = lane & 15;         // A-row (in-group batch) / B-col
    const int kblk = lane >> 4;         // k-block (8 contiguous k)
    const int b_a  = bt * 16 + c;       // global batch for x A-frags
    const int kh0  = wv * 256;          // wave's K-slice of H
    const int kx0  = wv * 128;          // wave's K-slice of D

    unsigned long long* const hqb = (unsigned long long*)h_buf;

    __shared__ bf16x8 hw[4][4][8][64];  // 128 KB: [wv][gate][ks][lane]
    __shared__ float  gbuf[4][16][67];  // partial-gate tiles

    // ---- prologue: h-weights -> LDS (each thread fills/reads its own slot)
#pragma unroll
    for (int g = 0; g < 4; ++g)
#pragma unroll
        for (int ks = 0; ks < 8; ++ks) {
            bf16x8 tf;
#pragma unroll
            for (int e = 0; e < 8; ++e)
                tf[e] = f2bf(Wh[(size_t)(kh0 + ks * 32 + kblk * 8 + e) * G4H
                                + g * H_ + j0 + c]);
            hw[wv][g][ks][lane] = tf;
        }

    // ---- x-weights -> registers (64 VGPRs), pinned vs rematerialization
    bf16x8 wxf[4][4];
#pragma unroll
    for (int g = 0; g < 4; ++g)
#pragma unroll
        for (int ks = 0; ks < 4; ++ks) {
            bf16x8 tf;
#pragma unroll
            for (int e = 0; e < 8; ++e)
                tf[e] = f2bf(Wx[(size_t)(kx0 + ks * 32 + kblk * 8 + e) * G4H
                                + g * H_ + j0 + c]);
            wxf[g][ks] = tf;
        }
#pragma unroll
    for (int g = 0; g < 4; ++g)
#pragma unroll
        for (int ks = 0; ks < 4; ++ks)
            asm volatile("" : "+v"(wxf[g][ks]));   // opaque: cannot re-load

    // ---- epilogue mapping: thread -> one (batch eb, hidden ej)
    const int eb = tid >> 4;
    const int ej = tid & 15;
    const float bi  = bias[0 * H_ + j0 + ej];
    const float bfv = bias[1 * H_ + j0 + ej];
    const float bgv = bias[2 * H_ + j0 + ej];
    const float bo  = bias[3 * H_ + j0 + ej];
    const int b_glob = bt * 16 + eb;
    const int j_glob = j0 + ej;

    float cstate = 0.0f;

    // ---- x-part for t=0 (h-independent)
    f32x4 acc[4] = {{0.f,0.f,0.f,0.f},{0.f,0.f,0.f,0.f},
                    {0.f,0.f,0.f,0.f},{0.f,0.f,0.f,0.f}};
    {
        const float* xr = x + ((size_t)b_a * T_ + 0) * D_ + kx0 + kblk * 8;
#pragma unroll
        for (int ks = 0; ks < 4; ++ks) {
            f32x4 lo = *(const f32x4*)(xr + ks * 32);
            f32x4 hi = *(const f32x4*)(xr + ks * 32 + 4);
            bf16x8 xa;
#pragma unroll
            for (int e = 0; e < 4; ++e) { xa[e] = f2bf(lo[e]); xa[e+4] = f2bf(hi[e]); }
#pragma unroll
            for (int g = 0; g < 4; ++g)
                acc[g] = __builtin_amdgcn_mfma_f32_16x16x32_bf16(xa, wxf[g][ks], acc[g], 0, 0, 0);
        }
    }

#pragma unroll 1
    for (int t = 0; t < T_; ++t) {
        // ---- poll h_t (data IS the flag), COALESCED: lane (c,kblk) reads
        // chunk q = wv*32 + ks*4 + kblk, row c -> 64 lanes = contiguous 1KB.
        // qidx = (((slot*4+bt)*128 + q)*16 + b)*2 + half
        const unsigned long long* hq = hqb
            + ((((size_t)(t & 3) * 4 + bt) * 128 + wv * 32 + kblk) * 16 + c) * 2;
        unsigned long long q[16];
        for (int cap = 1 << 18; cap > 0; --cap) {
#pragma unroll
            for (int ks = 0; ks < 8; ++ks) {
                q[2*ks]   = aloadq(hq + ks * 128);      // ks stride = 4 chunks
                q[2*ks+1] = aloadq(hq + ks * 128 + 1);
            }
            bool mine = true;
#pragma unroll
            for (int i = 0; i < 16; ++i) mine &= (q[i] != SENTQ);
            if (__all((int)mine)) break;
            __builtin_amdgcn_s_sleep(1);
        }

        // ---- h MFMAs (weights from LDS, 4 chains) ----
#pragma unroll
        for (int ks = 0; ks < 8; ++ks) {
            union { unsigned long long qq[2]; bf16x8 v; } ua;
            ua.qq[0] = q[2*ks]; ua.qq[1] = q[2*ks+1];   // k = 8q..8q+7
            bf16x8 w0 = hw[wv][0][ks][lane];
            bf16x8 w1 = hw[wv][1][ks][lane];
            bf16x8 w2 = hw[wv][2][ks][lane];
            bf16x8 w3 = hw[wv][3][ks][lane];
            acc[0] = __builtin_amdgcn_mfma_f32_16x16x32_bf16(ua.v, w0, acc[0], 0, 0, 0);
            acc[1] = __builtin_amdgcn_mfma_f32_16x16x32_bf16(ua.v, w1, acc[1], 0, 0, 0);
            acc[2] = __builtin_amdgcn_mfma_f32_16x16x32_bf16(ua.v, w2, acc[2], 0, 0, 0);
            acc[3] = __builtin_amdgcn_mfma_f32_16x16x32_bf16(ua.v, w3, acc[3], 0, 0, 0);
        }

        // ---- partials -> LDS (D layout: col = lane&15, row = kblk*4 + r) ----
#pragma unroll
        for (int g = 0; g < 4; ++g)
#pragma unroll
            for (int r = 0; r < 4; ++r)
                gbuf[wv][kblk * 4 + r][g * 16 + c] = acc[g][r];
        // sync1 + drain: orders last iter's tail stores (incl. re-sentinel of
        // slot t+2) before this iter's h-data store (sentinel-before-data).
        asm volatile("s_waitcnt vmcnt(0)" ::: "memory");
        __syncthreads();

        // ---- reduce 4 wave-partials + activations ----
        float gi = ((gbuf[0][eb][ 0+ej] + gbuf[1][eb][ 0+ej])
                  + (gbuf[2][eb][ 0+ej] + gbuf[3][eb][ 0+ej])) + bi;
        float gf = ((gbuf[0][eb][16+ej] + gbuf[1][eb][16+ej])
                  + (gbuf[2][eb][16+ej] + gbuf[3][eb][16+ej])) + bfv;
        float gg = ((gbuf[0][eb][32+ej] + gbuf[1][eb][32+ej])
                  + (gbuf[2][eb][32+ej] + gbuf[3][eb][32+ej])) + bgv;
        float go = ((gbuf[0][eb][48+ej] + gbuf[1][eb][48+ej])
                  + (gbuf[2][eb][48+ej] + gbuf[3][eb][48+ej])) + bo;

        float I = sigmoid_f(gi);
        float F = sigmoid_f(gf);
        float G = tanh_f(gg);
        float O = sigmoid_f(go);
        cstate = F * cstate + I * G;
        float hval = O * tanh_f(cstate);

        // ---- h store = THE signal (packed 8B per 4 threads, coalesced) ----
        unsigned int mybf = (unsigned int)(unsigned short)f2bf(hval);
        unsigned int p01  = mybf | (((unsigned int)__shfl_xor((int)mybf, 1, 64)) << 16);
        unsigned int p23  = (unsigned int)__shfl_xor((int)p01, 2, 64);
        if ((t + 1 < T_) && (ej & 3) == 0) {
            unsigned long long pk = (unsigned long long)p01
                                  | ((unsigned long long)p23 << 32);
            // chunk q = jt*2 + (ej>>3); qword half = (ej>>2)&1; row = eb
            unsigned long long* hp = hqb
                + (((size_t)(((t + 1) & 3) * 4 + bt) * 128 + jt * 2 + (ej >> 3)) * 16
                   + eb) * 2 + ((ej >> 2) & 1);
            astoreq(hp, pk);
        }
        __syncthreads();   // sync2: gbuf reads done before next iter's writes

        // ---- tail (off critical path): y, re-sentinel slot t+3, next x ----
        y[((size_t)b_glob * T_ + t) * H_ + j_glob] = hval;   // 64B / 16 lanes

        // re-sentinel ring slot t+3 (old h_{t-1}; all consumers provably done:
        // seeing h_t implies every WG passed (F) of t-1, hence its slot-(t-1)
        // reads). WG covers its OWN produced region: 2 chunks x 16 b x 2 halves.
        if (t + 1 < T_ && tid < 64) {
            int qch = jt * 2 + (tid >> 5);
            int bb  = (tid >> 1) & 15;
            int hf  = tid & 1;
            unsigned long long* sp = hqb
                + (((size_t)(((t + 3) & 3) * 4 + bt) * 128 + qch) * 16 + bb) * 2 + hf;
            astoreq(sp, SENTQ);
        }

        // next step's x-part
#pragma unroll
        for (int g = 0; g < 4; ++g)
            acc[g] = (f32x4){0.f,0.f,0.f,0.f};
        if (t + 1 < T_) {
            const float* xr = x + ((size_t)b_a * T_ + (t + 1)) * D_ + kx0 + kblk * 8;
#pragma unroll
            for (int ks = 0; ks < 4; ++ks) {
                f32x4 lo = *(const f32x4*)(xr + ks * 32);
                f32x4 hi = *(const f32x4*)(xr + ks * 32 + 4);
                bf16x8 xa;
#pragma unroll
                for (int e = 0; e < 4; ++e) { xa[e] = f2bf(lo[e]); xa[e+4] = f2bf(hi[e]); }
#pragma unroll
                for (int g = 0; g < 4; ++g)
                    acc[g] = __builtin_amdgcn_mfma_f32_16x16x32_bf16(xa, wxf[g][ks], acc[g], 0, 0, 0);
            }
        }
    }
}

extern "C" void kernel_launch(void* const* d_in, const int* in_sizes, int n_in,
                              void* d_out, int out_size, void* d_ws, size_t ws_size,
                              hipStream_t stream)
{
    const float* x    = (const float*)d_in[0];
    const float* Wx   = (const float*)d_in[1];
    const float* Wh   = (const float*)d_in[2];
    const float* bias = (const float*)d_in[3];
    float* y = (float*)d_out;

    short* h_buf = (short*)d_ws;   // 4 slots x 4 groups x 128 q x 16 b x 8 = 512 KB

    // Re-init the ring every call (replay-safe): slot0 = h_0 = zeros,
    // slots1..3 = sentinel.
    init_hbuf<<<dim3((4 * B_ * H_ / 2) / 256), dim3(256), 0, stream>>>(
        (unsigned int*)h_buf);

    lstm_persistent<<<dim3(NWG), dim3(256), 0, stream>>>(
        x, Wx, Wh, bias, y, h_buf);
}